// Round 8
// baseline (108.103 us; speedup 1.0000x reference)
//
#include <hip/hip_runtime.h>
#include <hip/hip_fp16.h>

// Problem constants (from reference setup_inputs)
#define BZ    32
#define NPTS  16384
#define NSMP  4096
#define KNB   64
#define NCH   6
#define RDISC 0.05f

#define WGS   256       // threads per wg == samples per wg (1 lane = 1 sample)
#define NPASS 16        // table chunks (buckets) of CROWS rows
#define CROWS 1024      // rows per chunk (NPTS / NPASS)

__device__ __forceinline__ unsigned pkh(float x, float y) {
    return (unsigned)__half_as_ushort(__float2half(x))
         | ((unsigned)__half_as_ushort(__float2half(y)) << 16);
}

// ---- pre-pass: pack feature table to fp16 rows padded to 16B --------------
__global__ __launch_bounds__(256) void pnpp_pack(
    const float* __restrict__ feat, uint4* __restrict__ ptab)
{
    const int r = blockIdx.x * 256 + threadIdx.x;      // row 0..524287
    const float* src = feat + (size_t)r * NCH;
    const float4 a = *(const float4*)src;              // 8B-aligned dwordx4
    const float2 b = *(const float2*)(src + 4);
    ptab[r] = make_uint4(pkh(a.x, a.y), pkh(a.z, a.w), pkh(b.x, b.y), 0u);
}

// ---- main kernel ----------------------------------------------------------
// wg = 256 samples, 1 lane = 1 sample. LDS = ent 32KB + chunk 16KB = 48KB
// -> 3 wg/CU = 12 waves/CU (R6 had 8; the walk is LDS-latency-bound, so
// wave concurrency is the lever). 16-bucket sort (R5-verified code): each
// lane histograms its 64 (idx,ind) entries into 2 packed u64 counters,
// prefix-sums, counting-scatters into ent[pos][tid]. Table walked in 16
// LDS-resident fp16 chunks; next chunk's global loads issued before the
// walk; walk prefetches the NEXT entry's ds_read_b16 so two independent
// LDS reads are in flight per thread. XCD swizzle keeps each batch's
// packed table resident in one XCD's L2.
template<bool PACKED>
__global__ __launch_bounds__(256, 3) void pnpp_main(
    const float* __restrict__ feat,     // [BZ*NPTS*NCH] f32
    const uint4* __restrict__ ptab,     // [BZ*NPTS] packed fp16 rows
    const int*   __restrict__ nk_idx,   // [NS*KNB]
    const float* __restrict__ nk_dist,  // [NS*KNB]
    const int*   __restrict__ fps_idx,  // [NS]
    float*       __restrict__ out)      // [NS*11]
{
    __shared__ unsigned short ent[KNB * WGS];   // 32KB sorted entries [pos][sample]
    __shared__ uint4 chunkbuf[CROWS];           // 16KB fp16 rows of current chunk

    const int tid = threadIdx.x;
    const int bid = blockIdx.x;
    // XCD swizzle (grid 512, multiple of 8): XCD k gets works [64k, 64k+64)
    const int w   = (bid & 7) * (gridDim.x >> 3) + (bid >> 3);
    const int wg0 = w * WGS;
    const int s   = wg0 + tid;          // this lane's sample
    const int b   = s >> 12;            // batch (4096 samples per batch)

    // Sampled point features first (global latency overlaps phase 0)
    const int pidx = fps_idx[s];
    const float* fsrow = feat + (size_t)pidx * NCH;
    const float4 fa  = *(const float4*)(fsrow);
    const float2 fb2 = *(const float2*)(fsrow + 4);

    // ---- phase 0: load 64 (idx,dist); pack entries; 16-bucket histogram
    unsigned er[32];                    // 64 u16 entries, 2 per dword
    unsigned long long c0 = 0, c1 = 0;  // 16 x 8-bit bucket counts
    {
        const int4*   ip = (const int4*)  (nk_idx  + (size_t)s * KNB);
        const float4* dp = (const float4*)(nk_dist + (size_t)s * KNB);
        #pragma unroll
        for (int c = 0; c < 16; ++c) {
            const int4   i4 = ip[c];
            const float4 d4 = dp[c];
            const unsigned e0 = (unsigned)i4.x | ((d4.x <= RDISC) ? 0x8000u : 0u);
            const unsigned e1 = (unsigned)i4.y | ((d4.y <= RDISC) ? 0x8000u : 0u);
            const unsigned e2 = (unsigned)i4.z | ((d4.z <= RDISC) ? 0x8000u : 0u);
            const unsigned e3 = (unsigned)i4.w | ((d4.w <= RDISC) ? 0x8000u : 0u);
            er[c * 2]     = e0 | (e1 << 16);
            er[c * 2 + 1] = e2 | (e3 << 16);
            #define HADD(ii) { const unsigned bk = ((unsigned)(ii)) >> 10;      \
                const unsigned long long inc = 1ull << ((bk & 7) * 8);          \
                if (bk < 8) c0 += inc; else c1 += inc; }
            HADD(i4.x) HADD(i4.y) HADD(i4.z) HADD(i4.w)
            #undef HADD
        }
    }

    // Exclusive prefix over the 16 bucket counts (packed bytes).
    unsigned long long p0 = 0, p1 = 0;
    {
        unsigned run = 0;
        #pragma unroll
        for (int k = 0; k < 8; ++k) {
            p0 |= (unsigned long long)run << (k * 8);
            run += (unsigned)((c0 >> (k * 8)) & 0xffULL);
        }
        #pragma unroll
        for (int k = 0; k < 8; ++k) {
            p1 |= (unsigned long long)run << (k * 8);
            run += (unsigned)((c1 >> (k * 8)) & 0xffULL);
        }
    }

    // ---- counting-scatter entries bucket-sorted into LDS [pos][sample]
    {
        unsigned long long b0 = p0, b1 = p1;
        #pragma unroll
        for (int k = 0; k < 64; ++k) {
            const unsigned e  = (k & 1) ? (er[k >> 1] >> 16) : (er[k >> 1] & 0xffffu);
            const unsigned bk = (e & 0x3fffu) >> 10;
            const unsigned sh = (bk & 7) * 8;
            const unsigned long long inc = 1ull << sh;
            unsigned pos;
            if (bk < 8) { pos = (unsigned)((b0 >> sh) & 0xffULL); b0 += inc; }
            else        { pos = (unsigned)((b1 >> sh) & 0xffULL); b1 += inc; }
            ent[pos * WGS + tid] = (unsigned short)e;
        }
    }

    const float fs0 = fa.x, fs1 = fa.y, fs2 = fa.z;
    const float fs3 = fa.w, fs4 = fb2.x, fs5 = fb2.y;
    const float qs1 = fs0*fs0 + fs1*fs1 + fs2*fs2;
    const float qs2 = fs3*fs3 + fs4*fs4 + fs5*fs5;

    const uint4* tb     = ptab + (size_t)b * NPTS;
    const float* fbatch = feat + (size_t)b * (NPTS * NCH);

    #define SLOAD(P, ST)                                                        \
        if (PACKED) {                                                           \
            _Pragma("unroll")                                                   \
            for (int i = 0; i < 4; ++i) ST[i] = tb[(P) * CROWS + i * WGS + tid];\
        } else {                                                                \
            _Pragma("unroll")                                                   \
            for (int i = 0; i < 4; ++i) {                                       \
                const int r = (P) * CROWS + i * WGS + tid;                      \
                const float* fr = fbatch + (size_t)r * NCH;                     \
                const float2 A = *(const float2*)(fr);                          \
                const float2 Bv = *(const float2*)(fr + 2);                     \
                const float2 Cv = *(const float2*)(fr + 4);                     \
                ST[i] = make_uint4(pkh(A.x, A.y), pkh(Bv.x, Bv.y),              \
                                   pkh(Cv.x, Cv.y), 0u);                        \
            }                                                                   \
        }
    #define SWRITE(ST)                                                          \
        { _Pragma("unroll")                                                     \
          for (int i = 0; i < 4; ++i) chunkbuf[i * WGS + tid] = ST[i]; }

    {
        uint4 st[4];
        SLOAD(0, st);
        SWRITE(st);
    }
    __syncthreads();   // chunk0 visible (ent is own-column only: no sync needed)

    float cntM = 0.f;
    float s0=0.f,s1=0.f,s2=0.f,s3=0.f,s4=0.f,s5=0.f;   // masked sums
    float m0=0.f,m1=0.f,m2=0.f;                        // unmasked xyz sums
    float cA=0.f,cB=0.f;                               // cosine sums

    for (int p = 0; p < NPASS; ++p) {
        uint4 st[4];
        if (p < NPASS - 1) { SLOAD(p + 1, st); }       // issue early

        const unsigned long long cl = (p < 8) ? p0 : p1;
        const unsigned long long ch = (p + 1 < 8) ? p0 : p1;
        const unsigned cur  = (unsigned)((cl >> ((p & 7) * 8)) & 0xffULL);
        const unsigned endv = (p == NPASS - 1) ? 64u
            : (unsigned)((ch >> (((p + 1) & 7) * 8)) & 0xffULL);
        int n = (int)(endv - cur);
        #pragma unroll
        for (int m = 1; m < 64; m <<= 1) {             // wave-max trip count
            const int o = __shfl_xor(n, m, 64);
            n = (o > n) ? o : n;
        }

        // depth-2 pipelined walk: next entry's b16 read issues alongside
        // the current row's b128 read (two independent LDS ops in flight).
        unsigned e = ent[(cur < 64u ? cur : 63u) * WGS + tid];
        for (int k = 0; k < n; ++k) {
            const unsigned nx = cur + (unsigned)k + 1u;
            const unsigned en = ent[(nx < 64u ? nx : 63u) * WGS + tid];
            const bool act = (cur + (unsigned)k) < endv;
            if (act) {
                const unsigned ridx = e & 0x3fffu;
                const uint4 v = chunkbuf[ridx & (CROWS - 1)];
                const float f0 = __half2float(__ushort_as_half((unsigned short)(v.x & 0xffffu)));
                const float f1 = __half2float(__ushort_as_half((unsigned short)(v.x >> 16)));
                const float f2 = __half2float(__ushort_as_half((unsigned short)(v.y & 0xffffu)));
                const float f3 = __half2float(__ushort_as_half((unsigned short)(v.y >> 16)));
                const float f4 = __half2float(__ushort_as_half((unsigned short)(v.z & 0xffffu)));
                const float f5 = __half2float(__ushort_as_half((unsigned short)(v.z >> 16)));
                const float ind = (e & 0x8000u) ? 1.f : 0.f;

                cntM += ind;
                s0 += ind*f0; s1 += ind*f1; s2 += ind*f2;
                s3 += ind*f3; s4 += ind*f4; s5 += ind*f5;
                m0 += f0; m1 += f1; m2 += f2;

                const float q1 = f0*f0 + f1*f1 + f2*f2;
                const float n1 = fs0*f0 + fs1*f1 + fs2*f2;
                cA += n1 * __builtin_amdgcn_rsqf(qs1 * q1);
                const float q2 = f3*f3 + f4*f4 + f5*f5;
                const float n2 = fs3*f3 + fs4*f4 + fs5*f5;
                cB += n2 * __builtin_amdgcn_rsqf(qs2 * q2);
            }
            e = en;
        }
        __syncthreads();                       // all done reading chunkbuf
        if (p < NPASS - 1) {
            SWRITE(st);                        // write next chunk
            __syncthreads();                   // visible before next walk
        }
    }

    // ---- finalize
    const float rc = __builtin_amdgcn_rcpf(cntM);
    const float d0 = fs0 - s0*rc, d1 = fs1 - s1*rc, d2 = fs2 - s2*rc;
    const float d3 = fs3 - s3*rc, d4 = fs4 - s4*rc, d5 = fs5 - s5*rc;
    const float ik = 1.f / (float)KNB;
    const float o6 = cA * ik, o7 = cB * ik;
    const float ax = m0 * ik, ay = m1 * ik, az = m2 * ik;
    const float o8  = fs1*az - fs2*ay;
    const float o9  = fs2*ax - fs0*az;
    const float o10 = fs0*ay - fs1*ax;

    // ---- LDS-staged coalesced output (reuse chunkbuf; loop barrier covers it)
    float* ostage = (float*)(void*)chunkbuf;   // 11264B of 16KB
    ostage[tid * 11 + 0]  = d0;
    ostage[tid * 11 + 1]  = d1;
    ostage[tid * 11 + 2]  = d2;
    ostage[tid * 11 + 3]  = d3;
    ostage[tid * 11 + 4]  = d4;
    ostage[tid * 11 + 5]  = d5;
    ostage[tid * 11 + 6]  = o6;
    ostage[tid * 11 + 7]  = o7;
    ostage[tid * 11 + 8]  = o8;
    ostage[tid * 11 + 9]  = o9;
    ostage[tid * 11 + 10] = o10;
    __syncthreads();
    const size_t obase = (size_t)wg0 * 11;
    #pragma unroll
    for (int i = 0; i < 11; ++i)
        out[obase + i * WGS + tid] = ostage[i * WGS + tid];
}

extern "C" void kernel_launch(void* const* d_in, const int* in_sizes, int n_in,
                              void* d_out, int out_size, void* d_ws, size_t ws_size,
                              hipStream_t stream) {
    const float* feat = (const float*)d_in[0];
    const int*   nki  = (const int*)  d_in[1];
    const float* nkd  = (const float*)d_in[2];
    const int*   fps  = (const int*)  d_in[3];
    float* out = (float*)d_out;

    const size_t need = (size_t)BZ * NPTS * sizeof(uint4);   // 8 MB
    const int blocks = (BZ * NSMP) / WGS;                    // 512

    if (ws_size >= need) {
        uint4* ptab = (uint4*)d_ws;
        pnpp_pack<<<dim3((BZ * NPTS) / 256), dim3(256), 0, stream>>>(feat, ptab);
        pnpp_main<true><<<dim3(blocks), dim3(WGS), 0, stream>>>(
            feat, ptab, nki, nkd, fps, out);
    } else {
        pnpp_main<false><<<dim3(blocks), dim3(WGS), 0, stream>>>(
            feat, (const uint4*)nullptr, nki, nkd, fps, out);
    }
}

// Round 9
// 55.838 us; speedup vs baseline: 1.9360x; 1.9360x over previous
//
#include <hip/hip_runtime.h>
#include <hip/hip_fp16.h>

// Problem constants (from reference setup_inputs)
#define BZ    32
#define NPTS  16384
#define NSMP  4096
#define KNB   64
#define NCH   6
#define RDISC 0.05f

#define WGS   512       // threads per wg == samples per wg (1 lane = 1 sample)
#define HROWS 8192      // rows per table half (2 passes over the batch table)

// Strategy (R9): no random vector-memory gathers, no runtime-trip walks.
// Each lane owns one sample and keeps its 64 packed (idx | inlier<<15)
// entries in 32 VGPRs. The batch's feature table is processed in 2 halves;
// each half is staged into LDS as fp16 SoA (uint2 f0..f3 + uint f4f5, 96KB).
// The walk is a fully-unrolled static 64-iteration loop per half: lanes
// whose entry falls outside the current half read row 0 (broadcast, free)
// and accumulate with a 0 multiplier. Everything register-resident ->
// full ILP on the independent ds_reads, no spills (R8's failure mode).
__global__ __launch_bounds__(512, 1) void pnpp_main(
    const float* __restrict__ feat,     // [BZ*NPTS*NCH] f32
    const int*   __restrict__ nk_idx,   // [NS*KNB]
    const float* __restrict__ nk_dist,  // [NS*KNB]
    const int*   __restrict__ fps_idx,  // [NS]
    float*       __restrict__ out)      // [NS*11]
{
    __shared__ uint2    tA[HROWS];      // 64KB: fp16 (f0,f1),(f2,f3)
    __shared__ unsigned tB[HROWS];      // 32KB: fp16 (f4,f5)

    const int tid = threadIdx.x;
    const int bid = blockIdx.x;
    // XCD swizzle (grid 256 = 8*32): XCD k gets works [32k,32k+32)
    // = batches [4k,4k+4) -> batch tables L2-resident per XCD.
    const int w   = (bid & 7) * (gridDim.x >> 3) + (bid >> 3);
    const int wg0 = w * WGS;
    const int s   = wg0 + tid;          // this lane's sample
    const int b   = s >> 12;            // batch (4096 samples per batch)

    // Sampled point features (only remaining random gather; tiny volume)
    const int pidx = fps_idx[s];
    const float* fsrow = feat + (size_t)pidx * NCH;
    const float4 fa  = *(const float4*)(fsrow);     // 8B-aligned dwordx4 ok
    const float2 fb2 = *(const float2*)(fsrow + 4);

    // ---- entries: 64 x (idx | inlier<<15), packed 2 per dword, registers
    unsigned er[32];
    {
        const int4*   ip = (const int4*)  (nk_idx  + (size_t)s * KNB);
        const float4* dp = (const float4*)(nk_dist + (size_t)s * KNB);
        #pragma unroll
        for (int c = 0; c < 16; ++c) {
            const int4   i4 = ip[c];
            const float4 d4 = dp[c];
            const unsigned e0 = (unsigned)i4.x | ((d4.x <= RDISC) ? 0x8000u : 0u);
            const unsigned e1 = (unsigned)i4.y | ((d4.y <= RDISC) ? 0x8000u : 0u);
            const unsigned e2 = (unsigned)i4.z | ((d4.z <= RDISC) ? 0x8000u : 0u);
            const unsigned e3 = (unsigned)i4.w | ((d4.w <= RDISC) ? 0x8000u : 0u);
            er[c * 2]     = e0 | (e1 << 16);
            er[c * 2 + 1] = e2 | (e3 << 16);
        }
    }

    const float fs0 = fa.x, fs1 = fa.y, fs2 = fa.z;
    const float fs3 = fa.w, fs4 = fb2.x, fs5 = fb2.y;
    const float qs1 = fs0*fs0 + fs1*fs1 + fs2*fs2;
    const float qs2 = fs3*fs3 + fs4*fs4 + fs5*fs5;

    const float* fbatch = feat + (size_t)b * (NPTS * NCH);

    // ---- accumulators (lane-private; no reductions anywhere)
    float cntM = 0.f;
    float s0=0.f,s1=0.f,s2=0.f,s3=0.f,s4=0.f,s5=0.f;   // masked sums
    float m0=0.f,m1=0.f,m2=0.f;                        // unmasked xyz sums
    float cA=0.f,cB=0.f;                               // cosine sums

    for (int hp = 0; hp < 2; ++hp) {
        // ---- stage half hp: 16 rows per thread, coalesced f32 reads,
        //      fp16 SoA LDS writes (2-dword + 1-dword, ~2-way banks: free)
        #pragma unroll
        for (int i = 0; i < HROWS / WGS; ++i) {
            const int r = i * WGS + tid;
            const float* fr = fbatch + (size_t)(hp * HROWS + r) * NCH;
            const float4 A  = *(const float4*)(fr);      // f0..f3
            const float2 Cv = *(const float2*)(fr + 4);  // f4,f5
            uint2 va;
            va.x = (unsigned)__half_as_ushort(__float2half(A.x))
                 | ((unsigned)__half_as_ushort(__float2half(A.y)) << 16);
            va.y = (unsigned)__half_as_ushort(__float2half(A.z))
                 | ((unsigned)__half_as_ushort(__float2half(A.w)) << 16);
            tA[r] = va;
            tB[r] = (unsigned)__half_as_ushort(__float2half(Cv.x))
                  | ((unsigned)__half_as_ushort(__float2half(Cv.y)) << 16);
        }
        __syncthreads();   // half visible to all waves

        // ---- static walk: 64 predicated iterations, all state in regs
        #pragma unroll
        for (int k = 0; k < 64; ++k) {
            const unsigned e    = (k & 1) ? (er[k >> 1] >> 16)
                                          : (er[k >> 1] & 0xffffu);
            const unsigned ridx = e & 0x3fffu;
            const bool act      = (int)(ridx >> 13) == hp;
            const int  r        = act ? (int)(ridx & (HROWS - 1)) : 0;

            const uint2    va = tA[r];
            const unsigned vb = tB[r];
            const float2 f01 = __half22float2(*(const __half2*)&va.x);
            const float2 f23 = __half22float2(*(const __half2*)&va.y);
            const float2 f45 = __half22float2(*(const __half2*)&vb);
            const float f0 = f01.x, f1 = f01.y, f2 = f23.x;
            const float f3 = f23.y, f4 = f45.x, f5 = f45.y;

            const float am = act ? 1.f : 0.f;
            const float fm = (act && (e & 0x8000u)) ? 1.f : 0.f;

            cntM += fm;
            s0 += fm*f0; s1 += fm*f1; s2 += fm*f2;
            s3 += fm*f3; s4 += fm*f4; s5 += fm*f5;
            m0 += am*f0; m1 += am*f1; m2 += am*f2;

            const float q1 = f0*f0 + f1*f1 + f2*f2;
            const float n1 = fs0*f0 + fs1*f1 + fs2*f2;
            cA += am * (n1 * __builtin_amdgcn_rsqf(qs1 * q1));
            const float q2 = f3*f3 + f4*f4 + f5*f5;
            const float n2 = fs3*f3 + fs4*f4 + fs5*f5;
            cB += am * (n2 * __builtin_amdgcn_rsqf(qs2 * q2));
        }
        __syncthreads();   // walk done before half is overwritten / reused
    }

    // ---- finalize
    const float rc = __builtin_amdgcn_rcpf(cntM);
    const float d0 = fs0 - s0*rc, d1 = fs1 - s1*rc, d2 = fs2 - s2*rc;
    const float d3 = fs3 - s3*rc, d4 = fs4 - s4*rc, d5 = fs5 - s5*rc;
    const float ik = 1.f / (float)KNB;
    const float o6 = cA * ik, o7 = cB * ik;
    const float ax = m0 * ik, ay = m1 * ik, az = m2 * ik;
    const float o8  = fs1*az - fs2*ay;
    const float o9  = fs2*ax - fs0*az;
    const float o10 = fs0*ay - fs1*ax;

    // ---- LDS-staged coalesced output (reuse tA; barrier above covers it)
    float* ostage = (float*)(void*)tA;   // 22528B of 64KB
    ostage[tid * 11 + 0]  = d0;
    ostage[tid * 11 + 1]  = d1;
    ostage[tid * 11 + 2]  = d2;
    ostage[tid * 11 + 3]  = d3;
    ostage[tid * 11 + 4]  = d4;
    ostage[tid * 11 + 5]  = d5;
    ostage[tid * 11 + 6]  = o6;
    ostage[tid * 11 + 7]  = o7;
    ostage[tid * 11 + 8]  = o8;
    ostage[tid * 11 + 9]  = o9;
    ostage[tid * 11 + 10] = o10;
    __syncthreads();
    const size_t obase = (size_t)wg0 * 11;
    #pragma unroll
    for (int i = 0; i < 11; ++i)
        out[obase + i * WGS + tid] = ostage[i * WGS + tid];
}

extern "C" void kernel_launch(void* const* d_in, const int* in_sizes, int n_in,
                              void* d_out, int out_size, void* d_ws, size_t ws_size,
                              hipStream_t stream) {
    const float* feat = (const float*)d_in[0];
    const int*   nki  = (const int*)  d_in[1];
    const float* nkd  = (const float*)d_in[2];
    const int*   fps  = (const int*)  d_in[3];
    float* out = (float*)d_out;

    const int blocks = (BZ * NSMP) / WGS;   // 256
    pnpp_main<<<dim3(blocks), dim3(WGS), 0, stream>>>(feat, nki, nkd, fps, out);
}